// Round 5
// baseline (341.868 us; speedup 1.0000x reference)
//
#include <hip/hip_runtime.h>
#include <math.h>

// Shapes: B=4096, IN=1024, H=1024, S=64, Q=16, OUT=1024
// ws layout:
//   [0,16MB)    h_int f32 [4096][1024]
//   [16,32MB)   A2 bf16 [4096][2048]  (cols 0-1023 = h_int, 1024-2047 = m_t)
//   [32,40MB)   BT bf16 [2048][2048]  (= W_og^T)
//   [40,41MB)   Wqs f32 [1025][64]
//   [41MB)      idx int[4096]; counter; list
//   [42,58MB)   Ahi bf16 [4096][2048]; then fix_scratch; then gemm4 partial Pb0
//   [58,74MB)   Alo bf16 [4096][2048]; then gemm4 partial Pb1
//   [74,78MB)   BThi bf16 [1024][2048]
//   [78,82MB)   BTlo bf16 [1024][2048]
// d_out (32MB) doubles as gemm1 split-K f32 partials before gemm4 overwrites it.

typedef __attribute__((ext_vector_type(4))) float floatx4;
typedef __attribute__((ext_vector_type(8))) short short8;
typedef __attribute__((ext_vector_type(4))) unsigned short ushortx4;

#define OUT_H_OFF 4194304
#define TAU 1e-4f
#define FIX_CAP 512

#define AS1 __attribute__((address_space(1)))
#define AS3 __attribute__((address_space(3)))
#define GLL(gptr, lptr) __builtin_amdgcn_global_load_lds((const AS1 void*)(gptr), (AS3 void*)(lptr), 16, 0, 0)

__device__ __forceinline__ unsigned short f2bf(float f) {
  unsigned int u = __float_as_uint(f);
  u += 0x7fffu + ((u >> 16) & 1u);   // RNE
  return (unsigned short)(u >> 16);
}
__device__ __forceinline__ float bf2f(unsigned short h) {
  return __uint_as_float(((unsigned int)h) << 16);
}

// ---------------- K1: BT[n][k] = bf16(W_og[k][n]), 2048x2048 ----------------
__global__ __launch_bounds__(256) void k_transpose(const float* __restrict__ W,
                                                   unsigned short* __restrict__ BT) {
  __shared__ float tile[64][65];
  const int k0 = blockIdx.x * 64, n0 = blockIdx.y * 64;
  const int t = threadIdx.x, c = t & 63, rr = t >> 6;
#pragma unroll
  for (int i = 0; i < 16; ++i) {
    int r = i * 4 + rr;
    tile[r][c] = W[(size_t)(k0 + r) * 2048 + n0 + c];
  }
  __syncthreads();
#pragma unroll
  for (int i = 0; i < 16; ++i) {
    int r = i * 4 + rr;  // n-local
    BT[(size_t)(n0 + r) * 2048 + k0 + c] = f2bf(tile[c][r]);
  }
}

// ---------------- K1b: split-convert A = [x|h] -> Ahi/Alo bf16 [4096][2048] --------
__global__ __launch_bounds__(256) void k_convA(const float* __restrict__ x_t, const float* __restrict__ h_prev,
                                               unsigned short* __restrict__ Ahi, unsigned short* __restrict__ Alo) {
  const int stride = gridDim.x * blockDim.x;
  for (int c = blockIdx.x * blockDim.x + threadIdx.x; c < 2097152; c += stride) {
    int m = c >> 9, kc = (c & 511) << 2;
    const float* src = (kc < 1024) ? (x_t + (size_t)m * 1024 + kc)
                                   : (h_prev + (size_t)m * 1024 + (kc - 1024));
    floatx4 v = *reinterpret_cast<const floatx4*>(src);
    ushortx4 hi, lo;
#pragma unroll
    for (int j = 0; j < 4; ++j) {
      hi[j] = f2bf(v[j]);
      lo[j] = f2bf(v[j] - bf2f(hi[j]));
    }
    *reinterpret_cast<ushortx4*>(&Ahi[(size_t)m * 2048 + kc]) = hi;
    *reinterpret_cast<ushortx4*>(&Alo[(size_t)m * 2048 + kc]) = lo;
  }
}

// ------- K1c: split-convert+transpose W_in [2048][1024] -> BThi/BTlo [1024][2048] -------
__global__ __launch_bounds__(256) void k_convB(const float* __restrict__ W_in,
                                               unsigned short* __restrict__ BThi, unsigned short* __restrict__ BTlo) {
  __shared__ float tile[64][65];
  const int k0 = blockIdx.x * 64, n0 = blockIdx.y * 64;
  const int t = threadIdx.x, c = t & 63, rr = t >> 6;
#pragma unroll
  for (int i = 0; i < 16; ++i) {
    int r = i * 4 + rr;
    tile[r][c] = W_in[(size_t)(k0 + r) * 1024 + n0 + c];
  }
  __syncthreads();
#pragma unroll
  for (int i = 0; i < 16; ++i) {
    int r = i * 4 + rr;  // n-local
    float v = tile[c][r];
    unsigned short hi = f2bf(v);
    BThi[(size_t)(n0 + r) * 2048 + k0 + c] = hi;
    BTlo[(size_t)(n0 + r) * 2048 + k0 + c] = f2bf(v - bf2f(hi));
  }
}

// -------- K2s: split-K GEMM1 partials: P[ks] = A @ W_in (K-half ks), 3-term split bf16 MFMA --------
// BM=128, BN=64, BK=32, 4 waves, 2-phase dbuf, XOR-swizzled LDS. grid (32,16,2).
__global__ __launch_bounds__(256) void k_gemm1s(const unsigned short* __restrict__ Ahi,
                                                const unsigned short* __restrict__ Alo,
                                                const unsigned short* __restrict__ BThi,
                                                const unsigned short* __restrict__ BTlo,
                                                float* __restrict__ P) {
  __shared__ __align__(16) unsigned short Ah[2 * 4096];
  __shared__ __align__(16) unsigned short Al[2 * 4096];
  __shared__ __align__(16) unsigned short Bh[2 * 2048];
  __shared__ __align__(16) unsigned short Bl[2 * 2048];
  const int t = threadIdx.x;
  const int lane = t & 63, w = t >> 6;
  const int wm = w >> 1, wn = w & 1;
  const int m0 = blockIdx.x * 128, n0 = blockIdx.y * 64;
  const int kb = blockIdx.z * 1024;
  const int lr = lane & 15, lk = lane >> 4;
  floatx4 acc[4][2];
  floatx4 zero = {0.f, 0.f, 0.f, 0.f};
#pragma unroll
  for (int mi = 0; mi < 4; ++mi)
#pragma unroll
    for (int ni = 0; ni < 2; ++ni) acc[mi][ni] = zero;

  auto stage = [&](int p, int kt) {
    const int k0 = kb + kt * 32;
#pragma unroll
    for (int j = 0; j < 2; ++j) {
      int cc = j * 256 + t;
      int row = cc >> 2, sl = cc & 3;
      int sg = sl ^ ((row >> 1) & 3);
      size_t ga = (size_t)(m0 + row) * 2048 + k0 + sg * 8;
      GLL(Ahi + ga, &Ah[p * 4096 + cc * 8]);
      GLL(Alo + ga, &Al[p * 4096 + cc * 8]);
    }
    {
      int cc = t;
      int row = cc >> 2, sl = cc & 3;
      int sg = sl ^ ((row >> 1) & 3);
      size_t gb = (size_t)(n0 + row) * 2048 + k0 + sg * 8;
      GLL(BThi + gb, &Bh[p * 2048 + cc * 8]);
      GLL(BTlo + gb, &Bl[p * 2048 + cc * 8]);
    }
  };
  auto compute = [&](int p) {
    short8 ah[4], al[4], bh[2], bl[2];
#pragma unroll
    for (int mi = 0; mi < 4; ++mi) {
      int row = wm * 64 + mi * 16 + lr;
      int sl = lk ^ ((row >> 1) & 3);
      ah[mi] = *reinterpret_cast<const short8*>(&Ah[p * 4096 + row * 32 + sl * 8]);
      al[mi] = *reinterpret_cast<const short8*>(&Al[p * 4096 + row * 32 + sl * 8]);
    }
#pragma unroll
    for (int ni = 0; ni < 2; ++ni) {
      int row = wn * 32 + ni * 16 + lr;
      int sl = lk ^ ((row >> 1) & 3);
      bh[ni] = *reinterpret_cast<const short8*>(&Bh[p * 2048 + row * 32 + sl * 8]);
      bl[ni] = *reinterpret_cast<const short8*>(&Bl[p * 2048 + row * 32 + sl * 8]);
    }
#pragma unroll
    for (int mi = 0; mi < 4; ++mi)
#pragma unroll
      for (int ni = 0; ni < 2; ++ni) {
        acc[mi][ni] = __builtin_amdgcn_mfma_f32_16x16x32_bf16(ah[mi], bh[ni], acc[mi][ni], 0, 0, 0);
        acc[mi][ni] = __builtin_amdgcn_mfma_f32_16x16x32_bf16(ah[mi], bl[ni], acc[mi][ni], 0, 0, 0);
        acc[mi][ni] = __builtin_amdgcn_mfma_f32_16x16x32_bf16(al[mi], bh[ni], acc[mi][ni], 0, 0, 0);
      }
  };

  stage(0, 0);
  __syncthreads();
  int cur = 0;
  for (int kt = 0; kt < 31; ++kt) {
    stage(cur ^ 1, kt + 1);
    compute(cur);
    __syncthreads();
    cur ^= 1;
  }
  compute(cur);

  float* Pp = P + (size_t)blockIdx.z * 4194304;
#pragma unroll
  for (int mi = 0; mi < 4; ++mi) {
#pragma unroll
    for (int ni = 0; ni < 2; ++ni) {
      int gn = n0 + wn * 32 + ni * 16 + lr;
      int gmb = m0 + wm * 64 + mi * 16 + lk * 4;
#pragma unroll
      for (int j = 0; j < 4; ++j) {
        Pp[(size_t)(gmb + j) * 1024 + gn] = acc[mi][ni][j];
      }
    }
  }
}

// ------- K2c: combine split-K partials -> h_int f32 + A2 bf16 -------
__global__ __launch_bounds__(256) void k_comb1(const float* __restrict__ P, const float* __restrict__ b_in,
                                               float* __restrict__ h_int, unsigned short* __restrict__ A2) {
  const int e = blockIdx.x * 256 + threadIdx.x;
  const int base = e * 8;
  const int m = base >> 10, c = base & 1023;
  floatx4 a0 = *reinterpret_cast<const floatx4*>(&P[base]);
  floatx4 a1 = *reinterpret_cast<const floatx4*>(&P[base + 4]);
  floatx4 b0 = *reinterpret_cast<const floatx4*>(&P[4194304 + base]);
  floatx4 b1 = *reinterpret_cast<const floatx4*>(&P[4194304 + base + 4]);
  floatx4 bi0 = *reinterpret_cast<const floatx4*>(&b_in[c]);
  floatx4 bi1 = *reinterpret_cast<const floatx4*>(&b_in[c + 4]);
  floatx4 h0, h1;
  ushortx4 p0, p1;
#pragma unroll
  for (int j = 0; j < 4; ++j) {
    float v = tanhf(a0[j] + b0[j] + bi0[j]);
    h0[j] = v; p0[j] = f2bf(v);
    float u = tanhf(a1[j] + b1[j] + bi1[j]);
    h1[j] = u; p1[j] = f2bf(u);
  }
  *reinterpret_cast<floatx4*>(&h_int[base]) = h0;
  *reinterpret_cast<floatx4*>(&h_int[base + 4]) = h1;
  *reinterpret_cast<ushortx4*>(&A2[(size_t)m * 2048 + c]) = p0;
  *reinterpret_cast<ushortx4*>(&A2[(size_t)m * 2048 + c + 4]) = p1;
}

// ---------------- K2f: fp32 fallback GEMM1 (used when ws too small) ----------------
__global__ __launch_bounds__(256) void k_gemm1(const float* __restrict__ x_t, const float* __restrict__ h_prev,
                                               const float* __restrict__ W_in, const float* __restrict__ b_in,
                                               float* __restrict__ h_int, unsigned short* __restrict__ A2) {
  __shared__ float As[16 * 128];
  __shared__ float Bs[16 * 64];
  const int t = threadIdx.x;
  const int m0 = blockIdx.x * 128, n0 = blockIdx.y * 64;
  const int ty = t >> 4, tx = t & 15;
  float acc[8][4];
#pragma unroll
  for (int i = 0; i < 8; ++i)
#pragma unroll
    for (int j = 0; j < 4; ++j) acc[i][j] = 0.f;
  for (int kt = 0; kt < 128; ++kt) {
    const int k0 = kt * 16;
    __syncthreads();
#pragma unroll
    for (int u = 0; u < 2; ++u) {
      int cc = t + u * 256;
      int row = cc >> 2, col4 = (cc & 3) << 2;
      int gk = k0 + col4;
      const float* src = (gk < 1024) ? (x_t + (size_t)(m0 + row) * 1024 + gk)
                                     : (h_prev + (size_t)(m0 + row) * 1024 + (gk - 1024));
      floatx4 v = *reinterpret_cast<const floatx4*>(src);
      As[(col4 + 0) * 128 + row] = v[0];
      As[(col4 + 1) * 128 + row] = v[1];
      As[(col4 + 2) * 128 + row] = v[2];
      As[(col4 + 3) * 128 + row] = v[3];
    }
    {
      int kr = t >> 4, c4 = (t & 15) << 2;
      *reinterpret_cast<floatx4*>(&Bs[kr * 64 + c4]) =
          *reinterpret_cast<const floatx4*>(&W_in[(size_t)(k0 + kr) * 1024 + n0 + c4]);
    }
    __syncthreads();
#pragma unroll
    for (int kk = 0; kk < 16; ++kk) {
      floatx4 a0 = *reinterpret_cast<const floatx4*>(&As[kk * 128 + ty * 8]);
      floatx4 a1 = *reinterpret_cast<const floatx4*>(&As[kk * 128 + ty * 8 + 4]);
      floatx4 b = *reinterpret_cast<const floatx4*>(&Bs[kk * 64 + tx * 4]);
#pragma unroll
      for (int j = 0; j < 4; ++j) {
        acc[0][j] += a0[0] * b[j]; acc[1][j] += a0[1] * b[j];
        acc[2][j] += a0[2] * b[j]; acc[3][j] += a0[3] * b[j];
        acc[4][j] += a1[0] * b[j]; acc[5][j] += a1[1] * b[j];
        acc[6][j] += a1[2] * b[j]; acc[7][j] += a1[3] * b[j];
      }
    }
  }
  const int nbase = n0 + tx * 4;
  floatx4 bias = *reinterpret_cast<const floatx4*>(&b_in[nbase]);
#pragma unroll
  for (int i = 0; i < 8; ++i) {
    int gm = m0 + ty * 8 + i;
    floatx4 tv; ushortx4 pk;
#pragma unroll
    for (int j = 0; j < 4; ++j) {
      float v = tanhf(acc[i][j] + bias[j]);
      tv[j] = v; pk[j] = f2bf(v);
    }
    *reinterpret_cast<floatx4*>(&h_int[(size_t)gm * 1024 + nbase]) = tv;
    *reinterpret_cast<ushortx4*>(&A2[(size_t)gm * 2048 + nbase]) = pk;
  }
}

// ---------------- K3: Wqs = W_q @ W_sel (+ fused bias row 1024) ----------------
__global__ __launch_bounds__(256) void k_wqs(const float* __restrict__ W_q, const float* __restrict__ b_q,
                                             const float* __restrict__ W_sel, const float* __restrict__ b_sel,
                                             float* __restrict__ Wqs) {
  const int t = threadIdx.x;
  const int w = t >> 6, lane = t & 63;
  const int h = blockIdx.x * 4 + w;
  if (h > 1024) return;
  const float* src = (h < 1024) ? (W_q + (size_t)h * 1024) : b_q;
  float acc = 0.f;
  for (int j = 0; j < 1024; j += 4) {
    floatx4 v = *reinterpret_cast<const floatx4*>(&src[j]);
    acc += v[0] * W_sel[(j + 0) * 64 + lane];
    acc += v[1] * W_sel[(j + 1) * 64 + lane];
    acc += v[2] * W_sel[(j + 2) * 64 + lane];
    acc += v[3] * W_sel[(j + 3) * 64 + lane];
  }
  if (h == 1024) acc += b_sel[lane];
  Wqs[(size_t)h * 64 + lane] = acc;
}

// ------- K4: logits = h_int @ Wqs + bqs; idx = argmax; flag rows w/ gap < TAU -------
__global__ __launch_bounds__(256) void k_argmax(const float* __restrict__ h_int, const float* __restrict__ Wqs,
                                                int* __restrict__ idx, int* __restrict__ counter,
                                                int* __restrict__ list, float tau) {
  __shared__ float Ahs[64 * 32];  // [k][r]
  __shared__ float Wt[64 * 64];   // [k][s]
  const int t = threadIdx.x;
  const int r0 = blockIdx.x * 32;
  const int w = t >> 6, lane = t & 63;
  float acc[8];
#pragma unroll
  for (int i = 0; i < 8; ++i) acc[i] = 0.f;

  for (int kt = 0; kt < 16; ++kt) {
    const int k0 = kt * 64;
    __syncthreads();
#pragma unroll
    for (int u = 0; u < 2; ++u) {
      int cc = t + u * 256;
      int r = cc >> 4, k4 = (cc & 15) << 2;
      floatx4 v = *reinterpret_cast<const floatx4*>(&h_int[(size_t)(r0 + r) * 1024 + k0 + k4]);
      Ahs[(k4 + 0) * 32 + r] = v[0];
      Ahs[(k4 + 1) * 32 + r] = v[1];
      Ahs[(k4 + 2) * 32 + r] = v[2];
      Ahs[(k4 + 3) * 32 + r] = v[3];
    }
#pragma unroll
    for (int u = 0; u < 4; ++u) {
      int cc = t + u * 256;
      int kr = cc >> 4, c4 = (cc & 15) << 2;
      *reinterpret_cast<floatx4*>(&Wt[kr * 64 + c4]) =
          *reinterpret_cast<const floatx4*>(&Wqs[(size_t)(k0 + kr) * 64 + c4]);
    }
    __syncthreads();
#pragma unroll
    for (int k = 0; k < 64; ++k) {
      float wv = Wt[k * 64 + lane];
      floatx4 a0 = *reinterpret_cast<const floatx4*>(&Ahs[k * 32 + w * 8]);
      floatx4 a1 = *reinterpret_cast<const floatx4*>(&Ahs[k * 32 + w * 8 + 4]);
      acc[0] += a0[0] * wv; acc[1] += a0[1] * wv; acc[2] += a0[2] * wv; acc[3] += a0[3] * wv;
      acc[4] += a1[0] * wv; acc[5] += a1[1] * wv; acc[6] += a1[2] * wv; acc[7] += a1[3] * wv;
    }
  }
  const float bqs = Wqs[1024 * 64 + lane];
#pragma unroll
  for (int i = 0; i < 8; ++i) {
    float v1 = acc[i] + bqs;
    int i1 = lane;
    float v2 = -__builtin_inff();
#pragma unroll
    for (int off = 32; off >= 1; off >>= 1) {
      float ov1 = __shfl_xor(v1, off);
      int oi1 = __shfl_xor(i1, off);
      float ov2 = __shfl_xor(v2, off);
      if (ov1 > v1 || (ov1 == v1 && oi1 < i1)) {
        v2 = fmaxf(v1, ov2); v1 = ov1; i1 = oi1;
      } else {
        v2 = fmaxf(v2, ov1);
      }
    }
    if (lane == 0) {
      int row = r0 + w * 8 + i;
      idx[row] = i1;
      if (v1 - v2 < tau) {
        int pos = atomicAdd(counter, 1);
        if (pos < 4096) list[pos] = row;
      }
    }
  }
}

// ------- K4b: exact fp32 partial pre-activations for flagged rows -------
__global__ __launch_bounds__(256) void k_fixA(const float* __restrict__ x_t, const float* __restrict__ h_prev,
                                              const float* __restrict__ W_in, const int* __restrict__ counter,
                                              const int* __restrict__ list, float* __restrict__ scratch) {
  __shared__ float cmb[256];
  const int t = threadIdx.x;
  const int cnt = min(counter[0], FIX_CAP);
  const int nwork = cnt * 8;
  for (int e = blockIdx.x; e < nwork; e += gridDim.x) {
    const int r = list[e >> 3], kc = e & 7;
    __syncthreads();
    {
      int k = kc * 256 + t;
      cmb[t] = (k < 1024) ? x_t[(size_t)r * 1024 + k] : h_prev[(size_t)r * 1024 + (k - 1024)];
    }
    __syncthreads();
    floatx4 a = {0.f, 0.f, 0.f, 0.f};
    const int n4 = t * 4;
    const float* Wb = W_in + (size_t)(kc * 256) * 1024 + n4;
    for (int kk = 0; kk < 256; ++kk) {
      float c = cmb[kk];
      floatx4 wv = *reinterpret_cast<const floatx4*>(Wb + (size_t)kk * 1024);
      a[0] += c * wv[0]; a[1] += c * wv[1]; a[2] += c * wv[2]; a[3] += c * wv[3];
    }
    *reinterpret_cast<floatx4*>(&scratch[(size_t)e * 1024 + n4]) = a;
  }
}

// ------- K4c: reduce partials -> exact h_int row -> logits -> argmax -> idx -------
__global__ __launch_bounds__(256) void k_fixB(const float* __restrict__ scratch, const float* __restrict__ b_in,
                                              const float* __restrict__ Wqs, const int* __restrict__ counter,
                                              const int* __restrict__ list, int* __restrict__ idx) {
  __shared__ float hrow[1024];
  __shared__ float partial[4 * 64];
  __shared__ float lg[64];
  const int t = threadIdx.x;
  const int cnt = min(counter[0], FIX_CAP);
  for (int e = blockIdx.x; e < cnt; e += gridDim.x) {
    const int r = list[e];
    __syncthreads();
    const int n4 = t * 4;
    floatx4 a = *reinterpret_cast<const floatx4*>(&b_in[n4]);
#pragma unroll
    for (int kc = 0; kc < 8; ++kc) {
      floatx4 p = *reinterpret_cast<const floatx4*>(&scratch[(size_t)(e * 8 + kc) * 1024 + n4]);
      a[0] += p[0]; a[1] += p[1]; a[2] += p[2]; a[3] += p[3];
    }
    hrow[n4 + 0] = tanhf(a[0]);
    hrow[n4 + 1] = tanhf(a[1]);
    hrow[n4 + 2] = tanhf(a[2]);
    hrow[n4 + 3] = tanhf(a[3]);
    __syncthreads();
    const int s = t & 63, part = t >> 6;
    float p = 0.f;
    for (int h = part * 256; h < part * 256 + 256; ++h) p += hrow[h] * Wqs[(size_t)h * 64 + s];
    partial[part * 64 + s] = p;
    __syncthreads();
    if (t < 64) lg[t] = partial[t] + partial[64 + t] + partial[128 + t] + partial[192 + t] + Wqs[1024 * 64 + t];
    __syncthreads();
    if (t == 0) {
      float bv = lg[0]; int bi = 0;
      for (int ss = 1; ss < 64; ++ss) {
        if (lg[ss] > bv) { bv = lg[ss]; bi = ss; }
      }
      idx[r] = bi;
    }
    __syncthreads();
  }
}

// ---------------- K5: mixture: angles -> cos -> m_t (block per row) ----------------
__global__ __launch_bounds__(256) void k_mix(const float* __restrict__ h_int, const int* __restrict__ idx,
                                             const float* __restrict__ Wm_enc, const float* __restrict__ theta,
                                             const float* __restrict__ Wm_dec, const float* __restrict__ b_m,
                                             unsigned short* __restrict__ A2) {
  __shared__ float hrow[1024];
  __shared__ float partial[256];
  __shared__ float expz[16];
  const int b = blockIdx.x, t = threadIdx.x;
  const int s = idx[b];
  *reinterpret_cast<floatx4*>(&hrow[t * 4]) =
      *reinterpret_cast<const floatx4*>(&h_int[(size_t)b * 1024 + t * 4]);
  __syncthreads();
  const int q = t & 15, g = t >> 4;
  const float* We = Wm_enc + (size_t)s * 16384;
  float p = 0.f;
#pragma unroll 8
  for (int j = 0; j < 64; ++j) {
    int h = g + j * 16;
    p += hrow[h] * We[h * 16 + q];
  }
  partial[t] = p;
  __syncthreads();
  if (t < 16) {
    float a = 0.f;
#pragma unroll
    for (int g2 = 0; g2 < 16; ++g2) a += partial[g2 * 16 + t];
    a += theta[s * 16 + t];
    expz[t] = cosf(a);
  }
  __syncthreads();
  const float* Wd = Wm_dec + (size_t)s * 16384;
  float e[16];
#pragma unroll
  for (int qq = 0; qq < 16; ++qq) e[qq] = expz[qq];
#pragma unroll
  for (int r = 0; r < 4; ++r) {
    int h = r * 256 + t;
    float v = b_m[h];
#pragma unroll
    for (int qq = 0; qq < 16; ++qq) v += e[qq] * Wd[qq * 1024 + h];
    A2[(size_t)b * 2048 + 1024 + h] = f2bf(tanhf(v));
  }
}

// ------- K6s: split-K GEMM4 partials: Pb[ks] = bf16(A2 @ BT^T), K-half ks. grid (32,16,2) -------
__global__ __launch_bounds__(256) void k_gemm4s(const unsigned short* __restrict__ A2,
                                                const unsigned short* __restrict__ BT,
                                                unsigned short* __restrict__ Pb0,
                                                unsigned short* __restrict__ Pb1) {
  __shared__ __align__(16) unsigned short As[2 * 4096];
  __shared__ __align__(16) unsigned short Bs[2 * 4096];
  const int t = threadIdx.x;
  const int lane = t & 63, w = t >> 6;
  const int wm = w >> 1, wn = w & 1;
  const int m0 = blockIdx.x * 128, n0 = blockIdx.y * 128;
  const int kb = blockIdx.z * 1024;
  const int lr = lane & 15, lk = lane >> 4;
  floatx4 acc[4][4];
  floatx4 zero = {0.f, 0.f, 0.f, 0.f};
#pragma unroll
  for (int mi = 0; mi < 4; ++mi)
#pragma unroll
    for (int ni = 0; ni < 4; ++ni) acc[mi][ni] = zero;

  auto stage = [&](int p, int kt) {
    const int k0 = kb + kt * 32;
#pragma unroll
    for (int j = 0; j < 2; ++j) {
      int cc = j * 256 + t;
      int row = cc >> 2, sl = cc & 3;
      int sg = sl ^ ((row >> 1) & 3);
      size_t ga = (size_t)(m0 + row) * 2048 + k0 + sg * 8;
      size_t gb = (size_t)(n0 + row) * 2048 + k0 + sg * 8;
      GLL(A2 + ga, &As[p * 4096 + cc * 8]);
      GLL(BT + gb, &Bs[p * 4096 + cc * 8]);
    }
  };
  auto compute = [&](int p) {
    short8 af[4], bf[4];
#pragma unroll
    for (int mi = 0; mi < 4; ++mi) {
      int row = wm * 64 + mi * 16 + lr;
      int sl = lk ^ ((row >> 1) & 3);
      af[mi] = *reinterpret_cast<const short8*>(&As[p * 4096 + row * 32 + sl * 8]);
    }
#pragma unroll
    for (int ni = 0; ni < 4; ++ni) {
      int row = wn * 64 + ni * 16 + lr;
      int sl = lk ^ ((row >> 1) & 3);
      bf[ni] = *reinterpret_cast<const short8*>(&Bs[p * 4096 + row * 32 + sl * 8]);
    }
#pragma unroll
    for (int mi = 0; mi < 4; ++mi)
#pragma unroll
      for (int ni = 0; ni < 4; ++ni)
        acc[mi][ni] = __builtin_amdgcn_mfma_f32_16x16x32_bf16(af[mi], bf[ni], acc[mi][ni], 0, 0, 0);
  };

  stage(0, 0);
  __syncthreads();
  int cur = 0;
  for (int kt = 0; kt < 31; ++kt) {
    stage(cur ^ 1, kt + 1);
    compute(cur);
    __syncthreads();
    cur ^= 1;
  }
  compute(cur);

  unsigned short* Pb = blockIdx.z ? Pb1 : Pb0;
#pragma unroll
  for (int mi = 0; mi < 4; ++mi) {
#pragma unroll
    for (int ni = 0; ni < 4; ++ni) {
      int gn = n0 + wn * 64 + ni * 16 + lr;
      int gmb = m0 + wm * 64 + mi * 16 + lk * 4;
#pragma unroll
      for (int j = 0; j < 4; ++j) {
        Pb[(size_t)(gmb + j) * 2048 + gn] = f2bf(acc[mi][ni][j]);
      }
    }
  }
}

// ------- K6c: combine gemm4 partials + bias -> tanh/split epilogue -> out -------
__global__ __launch_bounds__(256) void k_comb4(const unsigned short* __restrict__ Pb0,
                                               const unsigned short* __restrict__ Pb1,
                                               const float* __restrict__ b_og, float* __restrict__ out) {
  const int e = blockIdx.x * 256 + threadIdx.x;
  const int base = e * 8;
  const int m = base >> 11, c = base & 2047;
  ushortx4 a0 = *reinterpret_cast<const ushortx4*>(&Pb0[base]);
  ushortx4 a1 = *reinterpret_cast<const ushortx4*>(&Pb0[base + 4]);
  ushortx4 b0 = *reinterpret_cast<const ushortx4*>(&Pb1[base]);
  ushortx4 b1 = *reinterpret_cast<const ushortx4*>(&Pb1[base + 4]);
  floatx4 bi0 = *reinterpret_cast<const floatx4*>(&b_og[c]);
  floatx4 bi1 = *reinterpret_cast<const floatx4*>(&b_og[c + 4]);
  floatx4 v0, v1;
#pragma unroll
  for (int j = 0; j < 4; ++j) {
    v0[j] = bf2f(a0[j]) + bf2f(b0[j]) + bi0[j];
    v1[j] = bf2f(a1[j]) + bf2f(b1[j]) + bi1[j];
  }
  if (c < 1024) {
#pragma unroll
    for (int j = 0; j < 4; ++j) { v0[j] = tanhf(v0[j]); v1[j] = tanhf(v1[j]); }
    *reinterpret_cast<floatx4*>(&out[OUT_H_OFF + (size_t)m * 1024 + c]) = v0;
    *reinterpret_cast<floatx4*>(&out[OUT_H_OFF + (size_t)m * 1024 + c + 4]) = v1;
  } else {
    *reinterpret_cast<floatx4*>(&out[(size_t)m * 1024 + (c - 1024)]) = v0;
    *reinterpret_cast<floatx4*>(&out[(size_t)m * 1024 + (c - 1024) + 4]) = v1;
  }
}

// ---------------- K6f: fallback non-split GEMM4 (ws too small) ----------------
__global__ __launch_bounds__(256) void k_gemm4(const unsigned short* __restrict__ A2,
                                               const unsigned short* __restrict__ BT,
                                               const float* __restrict__ b_og, float* __restrict__ out) {
  __shared__ __align__(16) unsigned short As[2 * 4096];
  __shared__ __align__(16) unsigned short Bs[2 * 4096];
  const int t = threadIdx.x;
  const int lane = t & 63, w = t >> 6;
  const int wm = w >> 1, wn = w & 1;
  const int m0 = blockIdx.x * 128, n0 = blockIdx.y * 128;
  const int lr = lane & 15, lk = lane >> 4;
  floatx4 acc[4][4];
  floatx4 zero = {0.f, 0.f, 0.f, 0.f};
#pragma unroll
  for (int mi = 0; mi < 4; ++mi)
#pragma unroll
    for (int ni = 0; ni < 4; ++ni) acc[mi][ni] = zero;

  auto stage = [&](int p, int kt) {
    const int k0 = kt * 32;
#pragma unroll
    for (int j = 0; j < 2; ++j) {
      int cc = j * 256 + t;
      int row = cc >> 2, sl = cc & 3;
      int sg = sl ^ ((row >> 1) & 3);
      size_t ga = (size_t)(m0 + row) * 2048 + k0 + sg * 8;
      size_t gb = (size_t)(n0 + row) * 2048 + k0 + sg * 8;
      GLL(A2 + ga, &As[p * 4096 + cc * 8]);
      GLL(BT + gb, &Bs[p * 4096 + cc * 8]);
    }
  };
  auto compute = [&](int p) {
    short8 af[4], bf[4];
#pragma unroll
    for (int mi = 0; mi < 4; ++mi) {
      int row = wm * 64 + mi * 16 + lr;
      int sl = lk ^ ((row >> 1) & 3);
      af[mi] = *reinterpret_cast<const short8*>(&As[p * 4096 + row * 32 + sl * 8]);
    }
#pragma unroll
    for (int ni = 0; ni < 4; ++ni) {
      int row = wn * 64 + ni * 16 + lr;
      int sl = lk ^ ((row >> 1) & 3);
      bf[ni] = *reinterpret_cast<const short8*>(&Bs[p * 4096 + row * 32 + sl * 8]);
    }
#pragma unroll
    for (int mi = 0; mi < 4; ++mi)
#pragma unroll
      for (int ni = 0; ni < 4; ++ni)
        acc[mi][ni] = __builtin_amdgcn_mfma_f32_16x16x32_bf16(af[mi], bf[ni], acc[mi][ni], 0, 0, 0);
  };

  stage(0, 0);
  __syncthreads();
  int cur = 0;
  for (int kt = 0; kt < 63; ++kt) {
    stage(cur ^ 1, kt + 1);
    compute(cur);
    __syncthreads();
    cur ^= 1;
  }
  compute(cur);

#pragma unroll
  for (int mi = 0; mi < 4; ++mi) {
#pragma unroll
    for (int ni = 0; ni < 4; ++ni) {
      int gn = n0 + wn * 64 + ni * 16 + lr;
      float bias = b_og[gn];
      int gmb = m0 + wm * 64 + mi * 16 + lk * 4;
#pragma unroll
      for (int j = 0; j < 4; ++j) {
        int gm = gmb + j;
        float v = acc[mi][ni][j] + bias;
        if (gn < 1024) {
          out[OUT_H_OFF + (size_t)gm * 1024 + gn] = tanhf(v);
        } else {
          out[(size_t)gm * 1024 + (gn - 1024)] = v;
        }
      }
    }
  }
}

extern "C" void kernel_launch(void* const* d_in, const int* in_sizes, int n_in,
                              void* d_out, int out_size, void* d_ws, size_t ws_size,
                              hipStream_t stream) {
  (void)in_sizes; (void)n_in; (void)out_size;
  const float* x_t    = (const float*)d_in[0];
  const float* h_prev = (const float*)d_in[1];
  const float* W_in   = (const float*)d_in[2];
  const float* b_in   = (const float*)d_in[3];
  const float* W_q    = (const float*)d_in[4];
  const float* b_q    = (const float*)d_in[5];
  const float* W_sel  = (const float*)d_in[6];
  const float* b_sel  = (const float*)d_in[7];
  const float* Wm_enc = (const float*)d_in[8];
  const float* theta  = (const float*)d_in[9];
  const float* Wm_dec = (const float*)d_in[10];
  const float* b_m    = (const float*)d_in[11];
  const float* W_og   = (const float*)d_in[12];
  const float* b_og   = (const float*)d_in[13];
  float* out = (float*)d_out;

  char* ws = (char*)d_ws;
  float* h_int          = (float*)(ws);
  unsigned short* A2    = (unsigned short*)(ws + ((size_t)16 << 20));
  unsigned short* BT    = (unsigned short*)(ws + ((size_t)32 << 20));
  float* Wqs            = (float*)(ws + ((size_t)40 << 20));
  int* idx              = (int*)(ws + ((size_t)41 << 20));
  int* counter          = (int*)(ws + ((size_t)41 << 20) + 16384);
  int* list             = (int*)(ws + ((size_t)41 << 20) + 16384 + 64);
  unsigned short* Ahi   = (unsigned short*)(ws + ((size_t)42 << 20));
  unsigned short* Alo   = (unsigned short*)(ws + ((size_t)58 << 20));
  unsigned short* BThi  = (unsigned short*)(ws + ((size_t)74 << 20));
  unsigned short* BTlo  = (unsigned short*)(ws + ((size_t)78 << 20));
  float* fix_scratch    = (float*)(ws + ((size_t)42 << 20));   // reuses Ahi after gemm1s
  unsigned short* Pb0   = (unsigned short*)(ws + ((size_t)42 << 20));  // reuses Ahi after fixB
  unsigned short* Pb1   = (unsigned short*)(ws + ((size_t)58 << 20));  // reuses Alo

  const bool use_mfma = ws_size >= ((size_t)82 << 20);

  hipLaunchKernelGGL(k_transpose, dim3(32, 32), dim3(256), 0, stream, W_og, BT);
  hipLaunchKernelGGL(k_wqs, dim3(257), dim3(256), 0, stream, W_q, b_q, W_sel, b_sel, Wqs);
  hipMemsetAsync(counter, 0, 4, stream);

  if (use_mfma) {
    hipLaunchKernelGGL(k_convA, dim3(2048), dim3(256), 0, stream, x_t, h_prev, Ahi, Alo);
    hipLaunchKernelGGL(k_convB, dim3(32, 16), dim3(256), 0, stream, W_in, BThi, BTlo);
    // split-K GEMM1: f32 partials live in d_out (dead until gemm4s overw~ comb4)
    hipLaunchKernelGGL(k_gemm1s, dim3(32, 16, 2), dim3(256), 0, stream,
                       Ahi, Alo, BThi, BTlo, (float*)d_out);
    hipLaunchKernelGGL(k_comb1, dim3(2048), dim3(256), 0, stream,
                       (const float*)d_out, b_in, h_int, A2);
    hipLaunchKernelGGL(k_argmax, dim3(128), dim3(256), 0, stream, h_int, Wqs, idx, counter, list, TAU);
    hipLaunchKernelGGL(k_fixA, dim3(512), dim3(256), 0, stream,
                       x_t, h_prev, W_in, counter, list, fix_scratch);
    hipLaunchKernelGGL(k_fixB, dim3(64), dim3(256), 0, stream,
                       fix_scratch, b_in, Wqs, counter, list, idx);
    hipLaunchKernelGGL(k_mix, dim3(4096), dim3(256), 0, stream, h_int, idx, Wm_enc, theta, Wm_dec, b_m, A2);
    hipLaunchKernelGGL(k_gemm4s, dim3(32, 16, 2), dim3(256), 0, stream, A2, BT, Pb0, Pb1);
    hipLaunchKernelGGL(k_comb4, dim3(4096), dim3(256), 0, stream, Pb0, Pb1, b_og, out);
  } else {
    hipLaunchKernelGGL(k_gemm1, dim3(32, 16), dim3(256), 0, stream, x_t, h_prev, W_in, b_in, h_int, A2);
    hipLaunchKernelGGL(k_argmax, dim3(128), dim3(256), 0, stream, h_int, Wqs, idx, counter, list, 0.0f);
    hipLaunchKernelGGL(k_mix, dim3(4096), dim3(256), 0, stream, h_int, idx, Wm_enc, theta, Wm_dec, b_m, A2);
    hipLaunchKernelGGL(k_gemm4, dim3(32, 16), dim3(256), 0, stream, A2, BT, b_og, out);
  }
}

// Round 6
// 334.626 us; speedup vs baseline: 1.0216x; 1.0216x over previous
//
#include <hip/hip_runtime.h>
#include <math.h>

// Shapes: B=4096, IN=1024, H=1024, S=64, Q=16, OUT=1024
// ws layout:
//   [0,16MB)    h_int f32 [4096][1024]
//   [16,32MB)   A2 bf16 [4096][2048]  (cols 0-1023 = h_int, 1024-2047 = m_t)
//   [32,40MB)   BT bf16 [2048][2048]  (= W_og^T)
//   [40,41MB)   Wqs f32 [1025][64]
//   [41MB)      idx int[4096]; counter; list
//   [42,58MB)   Ahi bf16 [4096][2048]; reused as fixup scratch after gemm1m
//   [58,74MB)   Alo bf16 [4096][2048]
//   [74,78MB)   BThi bf16 [1024][2048]
//   [78,82MB)   BTlo bf16 [1024][2048]

typedef __attribute__((ext_vector_type(4))) float floatx4;
typedef __attribute__((ext_vector_type(8))) short short8;
typedef __attribute__((ext_vector_type(4))) unsigned short ushortx4;

#define OUT_H_OFF 4194304
#define TAU 1e-4f
#define FIX_CAP 512

#define AS1 __attribute__((address_space(1)))
#define AS3 __attribute__((address_space(3)))
#define GLL(gptr, lptr) __builtin_amdgcn_global_load_lds((const AS1 void*)(gptr), (AS3 void*)(lptr), 16, 0, 0)

__device__ __forceinline__ unsigned short f2bf(float f) {
  unsigned int u = __float_as_uint(f);
  u += 0x7fffu + ((u >> 16) & 1u);   // RNE
  return (unsigned short)(u >> 16);
}
__device__ __forceinline__ float bf2f(unsigned short h) {
  return __uint_as_float(((unsigned int)h) << 16);
}

// ---------------- K1: BT[n][k] = bf16(W_og[k][n]), 2048x2048 ----------------
__global__ __launch_bounds__(256) void k_transpose(const float* __restrict__ W,
                                                   unsigned short* __restrict__ BT) {
  __shared__ float tile[64][65];
  const int k0 = blockIdx.x * 64, n0 = blockIdx.y * 64;
  const int t = threadIdx.x, c = t & 63, rr = t >> 6;
#pragma unroll
  for (int i = 0; i < 16; ++i) {
    int r = i * 4 + rr;
    tile[r][c] = W[(size_t)(k0 + r) * 2048 + n0 + c];
  }
  __syncthreads();
#pragma unroll
  for (int i = 0; i < 16; ++i) {
    int r = i * 4 + rr;  // n-local
    BT[(size_t)(n0 + r) * 2048 + k0 + c] = f2bf(tile[c][r]);
  }
}

// ---------------- K1b: split-convert A = [x|h] -> Ahi/Alo bf16 [4096][2048] --------
__global__ __launch_bounds__(256) void k_convA(const float* __restrict__ x_t, const float* __restrict__ h_prev,
                                               unsigned short* __restrict__ Ahi, unsigned short* __restrict__ Alo) {
  const int stride = gridDim.x * blockDim.x;
  for (int c = blockIdx.x * blockDim.x + threadIdx.x; c < 2097152; c += stride) {
    int m = c >> 9, kc = (c & 511) << 2;
    const float* src = (kc < 1024) ? (x_t + (size_t)m * 1024 + kc)
                                   : (h_prev + (size_t)m * 1024 + (kc - 1024));
    floatx4 v = *reinterpret_cast<const floatx4*>(src);
    ushortx4 hi, lo;
#pragma unroll
    for (int j = 0; j < 4; ++j) {
      hi[j] = f2bf(v[j]);
      lo[j] = f2bf(v[j] - bf2f(hi[j]));
    }
    *reinterpret_cast<ushortx4*>(&Ahi[(size_t)m * 2048 + kc]) = hi;
    *reinterpret_cast<ushortx4*>(&Alo[(size_t)m * 2048 + kc]) = lo;
  }
}

// ------- K1c: split-convert+transpose W_in [2048][1024] -> BThi/BTlo [1024][2048] -------
__global__ __launch_bounds__(256) void k_convB(const float* __restrict__ W_in,
                                               unsigned short* __restrict__ BThi, unsigned short* __restrict__ BTlo) {
  __shared__ float tile[64][65];
  const int k0 = blockIdx.x * 64, n0 = blockIdx.y * 64;
  const int t = threadIdx.x, c = t & 63, rr = t >> 6;
#pragma unroll
  for (int i = 0; i < 16; ++i) {
    int r = i * 4 + rr;
    tile[r][c] = W_in[(size_t)(k0 + r) * 1024 + n0 + c];
  }
  __syncthreads();
#pragma unroll
  for (int i = 0; i < 16; ++i) {
    int r = i * 4 + rr;  // n-local
    float v = tile[c][r];
    unsigned short hi = f2bf(v);
    BThi[(size_t)(n0 + r) * 2048 + k0 + c] = hi;
    BTlo[(size_t)(n0 + r) * 2048 + k0 + c] = f2bf(v - bf2f(hi));
  }
}

// -------- K2m: h_int = tanh(A @ W_in + b_in), 3-term split bf16 MFMA --------
// BM=128, BN=64, BK=32, 4 waves. 3-buffer LDS, depth-2 prefetch, counted vmcnt,
// raw s_barrier (no vmcnt(0) drain in steady state). XOR-swizzled LDS (conflict-free).
__global__ __launch_bounds__(256) void k_gemm1m(const unsigned short* __restrict__ Ahi,
                                                const unsigned short* __restrict__ Alo,
                                                const unsigned short* __restrict__ BThi,
                                                const unsigned short* __restrict__ BTlo,
                                                const float* __restrict__ b_in,
                                                float* __restrict__ h_int, unsigned short* __restrict__ A2) {
  __shared__ __align__(16) unsigned short Ah[3 * 4096];  // [buf][128*32]
  __shared__ __align__(16) unsigned short Al[3 * 4096];
  __shared__ __align__(16) unsigned short Bh[3 * 2048];  // [buf][64*32]
  __shared__ __align__(16) unsigned short Bl[3 * 2048];
  const int t = threadIdx.x;
  const int lane = t & 63, w = t >> 6;
  const int wm = w >> 1, wn = w & 1;
  const int m0 = blockIdx.x * 128, n0 = blockIdx.y * 64;
  const int lr = lane & 15, lk = lane >> 4;
  floatx4 acc[4][2];
  floatx4 zero = {0.f, 0.f, 0.f, 0.f};
#pragma unroll
  for (int mi = 0; mi < 4; ++mi)
#pragma unroll
    for (int ni = 0; ni < 2; ++ni) acc[mi][ni] = zero;

  auto stage = [&](int p, int kt) {   // 6 GLL per thread
    const int k0 = kt * 32;
#pragma unroll
    for (int j = 0; j < 2; ++j) {
      int cc = j * 256 + t;
      int row = cc >> 2, sl = cc & 3;
      int sg = sl ^ ((row >> 1) & 3);
      size_t ga = (size_t)(m0 + row) * 2048 + k0 + sg * 8;
      GLL(Ahi + ga, &Ah[p * 4096 + cc * 8]);
      GLL(Alo + ga, &Al[p * 4096 + cc * 8]);
    }
    {
      int cc = t;
      int row = cc >> 2, sl = cc & 3;
      int sg = sl ^ ((row >> 1) & 3);
      size_t gb = (size_t)(n0 + row) * 2048 + k0 + sg * 8;
      GLL(BThi + gb, &Bh[p * 2048 + cc * 8]);
      GLL(BTlo + gb, &Bl[p * 2048 + cc * 8]);
    }
  };
  auto compute = [&](int p) {
    short8 ah[4], al[4], bh[2], bl[2];
#pragma unroll
    for (int mi = 0; mi < 4; ++mi) {
      int row = wm * 64 + mi * 16 + lr;
      int sl = lk ^ ((row >> 1) & 3);
      ah[mi] = *reinterpret_cast<const short8*>(&Ah[p * 4096 + row * 32 + sl * 8]);
      al[mi] = *reinterpret_cast<const short8*>(&Al[p * 4096 + row * 32 + sl * 8]);
    }
#pragma unroll
    for (int ni = 0; ni < 2; ++ni) {
      int row = wn * 32 + ni * 16 + lr;
      int sl = lk ^ ((row >> 1) & 3);
      bh[ni] = *reinterpret_cast<const short8*>(&Bh[p * 2048 + row * 32 + sl * 8]);
      bl[ni] = *reinterpret_cast<const short8*>(&Bl[p * 2048 + row * 32 + sl * 8]);
    }
#pragma unroll
    for (int mi = 0; mi < 4; ++mi)
#pragma unroll
      for (int ni = 0; ni < 2; ++ni) {
        acc[mi][ni] = __builtin_amdgcn_mfma_f32_16x16x32_bf16(ah[mi], bh[ni], acc[mi][ni], 0, 0, 0);
        acc[mi][ni] = __builtin_amdgcn_mfma_f32_16x16x32_bf16(ah[mi], bl[ni], acc[mi][ni], 0, 0, 0);
        acc[mi][ni] = __builtin_amdgcn_mfma_f32_16x16x32_bf16(al[mi], bh[ni], acc[mi][ni], 0, 0, 0);
      }
  };

  stage(0, 0);
  stage(1, 1);
  for (int kt = 0; kt < 64; ++kt) {
    __builtin_amdgcn_sched_barrier(0);
    if (kt < 63) {
      asm volatile("s_waitcnt vmcnt(6)" ::: "memory");   // drain only kt's 6 loads
    } else {
      asm volatile("s_waitcnt vmcnt(0)" ::: "memory");
    }
    __builtin_amdgcn_s_barrier();                         // raw barrier: no full drain
    __builtin_amdgcn_sched_barrier(0);
    if (kt + 2 < 64) stage((kt + 2) % 3, kt + 2);         // issue-early, 2 steps ahead
    compute(kt % 3);
  }

#pragma unroll
  for (int mi = 0; mi < 4; ++mi) {
#pragma unroll
    for (int ni = 0; ni < 2; ++ni) {
      int gn = n0 + wn * 32 + ni * 16 + lr;  // 0..1023
      float bias = b_in[gn];
      int gmb = m0 + wm * 64 + mi * 16 + lk * 4;
#pragma unroll
      for (int j = 0; j < 4; ++j) {
        int gm = gmb + j;
        float v = tanhf(acc[mi][ni][j] + bias);
        h_int[(size_t)gm * 1024 + gn] = v;
        A2[(size_t)gm * 2048 + gn] = f2bf(v);
      }
    }
  }
}

// ---------------- K2f: fp32 fallback GEMM1 (used when ws too small) ----------------
__global__ __launch_bounds__(256) void k_gemm1(const float* __restrict__ x_t, const float* __restrict__ h_prev,
                                               const float* __restrict__ W_in, const float* __restrict__ b_in,
                                               float* __restrict__ h_int, unsigned short* __restrict__ A2) {
  __shared__ float As[16 * 128];
  __shared__ float Bs[16 * 64];
  const int t = threadIdx.x;
  const int m0 = blockIdx.x * 128, n0 = blockIdx.y * 64;
  const int ty = t >> 4, tx = t & 15;
  float acc[8][4];
#pragma unroll
  for (int i = 0; i < 8; ++i)
#pragma unroll
    for (int j = 0; j < 4; ++j) acc[i][j] = 0.f;
  for (int kt = 0; kt < 128; ++kt) {
    const int k0 = kt * 16;
    __syncthreads();
#pragma unroll
    for (int u = 0; u < 2; ++u) {
      int cc = t + u * 256;
      int row = cc >> 2, col4 = (cc & 3) << 2;
      int gk = k0 + col4;
      const float* src = (gk < 1024) ? (x_t + (size_t)(m0 + row) * 1024 + gk)
                                     : (h_prev + (size_t)(m0 + row) * 1024 + (gk - 1024));
      floatx4 v = *reinterpret_cast<const floatx4*>(src);
      As[(col4 + 0) * 128 + row] = v[0];
      As[(col4 + 1) * 128 + row] = v[1];
      As[(col4 + 2) * 128 + row] = v[2];
      As[(col4 + 3) * 128 + row] = v[3];
    }
    {
      int kr = t >> 4, c4 = (t & 15) << 2;
      *reinterpret_cast<floatx4*>(&Bs[kr * 64 + c4]) =
          *reinterpret_cast<const floatx4*>(&W_in[(size_t)(k0 + kr) * 1024 + n0 + c4]);
    }
    __syncthreads();
#pragma unroll
    for (int kk = 0; kk < 16; ++kk) {
      floatx4 a0 = *reinterpret_cast<const floatx4*>(&As[kk * 128 + ty * 8]);
      floatx4 a1 = *reinterpret_cast<const floatx4*>(&As[kk * 128 + ty * 8 + 4]);
      floatx4 b = *reinterpret_cast<const floatx4*>(&Bs[kk * 64 + tx * 4]);
#pragma unroll
      for (int j = 0; j < 4; ++j) {
        acc[0][j] += a0[0] * b[j]; acc[1][j] += a0[1] * b[j];
        acc[2][j] += a0[2] * b[j]; acc[3][j] += a0[3] * b[j];
        acc[4][j] += a1[0] * b[j]; acc[5][j] += a1[1] * b[j];
        acc[6][j] += a1[2] * b[j]; acc[7][j] += a1[3] * b[j];
      }
    }
  }
  const int nbase = n0 + tx * 4;
  floatx4 bias = *reinterpret_cast<const floatx4*>(&b_in[nbase]);
#pragma unroll
  for (int i = 0; i < 8; ++i) {
    int gm = m0 + ty * 8 + i;
    floatx4 tv; ushortx4 pk;
#pragma unroll
    for (int j = 0; j < 4; ++j) {
      float v = tanhf(acc[i][j] + bias[j]);
      tv[j] = v; pk[j] = f2bf(v);
    }
    *reinterpret_cast<floatx4*>(&h_int[(size_t)gm * 1024 + nbase]) = tv;
    *reinterpret_cast<ushortx4*>(&A2[(size_t)gm * 2048 + nbase]) = pk;
  }
}

// ---------------- K3: Wqs = W_q @ W_sel (+ fused bias row 1024) ----------------
__global__ __launch_bounds__(256) void k_wqs(const float* __restrict__ W_q, const float* __restrict__ b_q,
                                             const float* __restrict__ W_sel, const float* __restrict__ b_sel,
                                             float* __restrict__ Wqs) {
  const int t = threadIdx.x;
  const int w = t >> 6, lane = t & 63;
  const int h = blockIdx.x * 4 + w;
  if (h > 1024) return;
  const float* src = (h < 1024) ? (W_q + (size_t)h * 1024) : b_q;
  float acc = 0.f;
  for (int j = 0; j < 1024; j += 4) {
    floatx4 v = *reinterpret_cast<const floatx4*>(&src[j]);
    acc += v[0] * W_sel[(j + 0) * 64 + lane];
    acc += v[1] * W_sel[(j + 1) * 64 + lane];
    acc += v[2] * W_sel[(j + 2) * 64 + lane];
    acc += v[3] * W_sel[(j + 3) * 64 + lane];
  }
  if (h == 1024) acc += b_sel[lane];
  Wqs[(size_t)h * 64 + lane] = acc;
}

// ------- K4: logits = h_int @ Wqs + bqs; idx = argmax; flag rows w/ gap < TAU -------
__global__ __launch_bounds__(256) void k_argmax(const float* __restrict__ h_int, const float* __restrict__ Wqs,
                                                int* __restrict__ idx, int* __restrict__ counter,
                                                int* __restrict__ list, float tau) {
  __shared__ float Ahs[64 * 32];  // [k][r]
  __shared__ float Wt[64 * 64];   // [k][s]
  const int t = threadIdx.x;
  const int r0 = blockIdx.x * 32;
  const int w = t >> 6, lane = t & 63;
  float acc[8];
#pragma unroll
  for (int i = 0; i < 8; ++i) acc[i] = 0.f;

  for (int kt = 0; kt < 16; ++kt) {
    const int k0 = kt * 64;
    __syncthreads();
#pragma unroll
    for (int u = 0; u < 2; ++u) {
      int cc = t + u * 256;
      int r = cc >> 4, k4 = (cc & 15) << 2;
      floatx4 v = *reinterpret_cast<const floatx4*>(&h_int[(size_t)(r0 + r) * 1024 + k0 + k4]);
      Ahs[(k4 + 0) * 32 + r] = v[0];
      Ahs[(k4 + 1) * 32 + r] = v[1];
      Ahs[(k4 + 2) * 32 + r] = v[2];
      Ahs[(k4 + 3) * 32 + r] = v[3];
    }
#pragma unroll
    for (int u = 0; u < 4; ++u) {
      int cc = t + u * 256;
      int kr = cc >> 4, c4 = (cc & 15) << 2;
      *reinterpret_cast<floatx4*>(&Wt[kr * 64 + c4]) =
          *reinterpret_cast<const floatx4*>(&Wqs[(size_t)(k0 + kr) * 64 + c4]);
    }
    __syncthreads();
#pragma unroll
    for (int k = 0; k < 64; ++k) {
      float wv = Wt[k * 64 + lane];
      floatx4 a0 = *reinterpret_cast<const floatx4*>(&Ahs[k * 32 + w * 8]);
      floatx4 a1 = *reinterpret_cast<const floatx4*>(&Ahs[k * 32 + w * 8 + 4]);
      acc[0] += a0[0] * wv; acc[1] += a0[1] * wv; acc[2] += a0[2] * wv; acc[3] += a0[3] * wv;
      acc[4] += a1[0] * wv; acc[5] += a1[1] * wv; acc[6] += a1[2] * wv; acc[7] += a1[3] * wv;
    }
  }
  const float bqs = Wqs[1024 * 64 + lane];
#pragma unroll
  for (int i = 0; i < 8; ++i) {
    float v1 = acc[i] + bqs;
    int i1 = lane;
    float v2 = -__builtin_inff();
#pragma unroll
    for (int off = 32; off >= 1; off >>= 1) {
      float ov1 = __shfl_xor(v1, off);
      int oi1 = __shfl_xor(i1, off);
      float ov2 = __shfl_xor(v2, off);
      if (ov1 > v1 || (ov1 == v1 && oi1 < i1)) {
        v2 = fmaxf(v1, ov2); v1 = ov1; i1 = oi1;
      } else {
        v2 = fmaxf(v2, ov1);
      }
    }
    if (lane == 0) {
      int row = r0 + w * 8 + i;
      idx[row] = i1;
      if (v1 - v2 < tau) {
        int pos = atomicAdd(counter, 1);
        if (pos < 4096) list[pos] = row;
      }
    }
  }
}

// ------- K4b: exact fp32 partial pre-activations for flagged rows -------
__global__ __launch_bounds__(256) void k_fixA(const float* __restrict__ x_t, const float* __restrict__ h_prev,
                                              const float* __restrict__ W_in, const int* __restrict__ counter,
                                              const int* __restrict__ list, float* __restrict__ scratch) {
  __shared__ float cmb[256];
  const int t = threadIdx.x;
  const int cnt = min(counter[0], FIX_CAP);
  const int nwork = cnt * 8;
  for (int e = blockIdx.x; e < nwork; e += gridDim.x) {
    const int r = list[e >> 3], kc = e & 7;
    __syncthreads();
    {
      int k = kc * 256 + t;
      cmb[t] = (k < 1024) ? x_t[(size_t)r * 1024 + k] : h_prev[(size_t)r * 1024 + (k - 1024)];
    }
    __syncthreads();
    floatx4 a = {0.f, 0.f, 0.f, 0.f};
    const int n4 = t * 4;
    const float* Wb = W_in + (size_t)(kc * 256) * 1024 + n4;
    for (int kk = 0; kk < 256; ++kk) {
      float c = cmb[kk];
      floatx4 wv = *reinterpret_cast<const floatx4*>(Wb + (size_t)kk * 1024);
      a[0] += c * wv[0]; a[1] += c * wv[1]; a[2] += c * wv[2]; a[3] += c * wv[3];
    }
    *reinterpret_cast<floatx4*>(&scratch[(size_t)e * 1024 + n4]) = a;
  }
}

// ------- K4c: reduce partials -> exact h_int row -> logits -> argmax -> idx -------
__global__ __launch_bounds__(256) void k_fixB(const float* __restrict__ scratch, const float* __restrict__ b_in,
                                              const float* __restrict__ Wqs, const int* __restrict__ counter,
                                              const int* __restrict__ list, int* __restrict__ idx) {
  __shared__ float hrow[1024];
  __shared__ float partial[4 * 64];
  __shared__ float lg[64];
  const int t = threadIdx.x;
  const int cnt = min(counter[0], FIX_CAP);
  for (int e = blockIdx.x; e < cnt; e += gridDim.x) {
    const int r = list[e];
    __syncthreads();
    const int n4 = t * 4;
    floatx4 a = *reinterpret_cast<const floatx4*>(&b_in[n4]);
#pragma unroll
    for (int kc = 0; kc < 8; ++kc) {
      floatx4 p = *reinterpret_cast<const floatx4*>(&scratch[(size_t)(e * 8 + kc) * 1024 + n4]);
      a[0] += p[0]; a[1] += p[1]; a[2] += p[2]; a[3] += p[3];
    }
    hrow[n4 + 0] = tanhf(a[0]);
    hrow[n4 + 1] = tanhf(a[1]);
    hrow[n4 + 2] = tanhf(a[2]);
    hrow[n4 + 3] = tanhf(a[3]);
    __syncthreads();
    const int s = t & 63, part = t >> 6;
    float p = 0.f;
    for (int h = part * 256; h < part * 256 + 256; ++h) p += hrow[h] * Wqs[(size_t)h * 64 + s];
    partial[part * 64 + s] = p;
    __syncthreads();
    if (t < 64) lg[t] = partial[t] + partial[64 + t] + partial[128 + t] + partial[192 + t] + Wqs[1024 * 64 + t];
    __syncthreads();
    if (t == 0) {
      float bv = lg[0]; int bi = 0;
      for (int ss = 1; ss < 64; ++ss) {
        if (lg[ss] > bv) { bv = lg[ss]; bi = ss; }
      }
      idx[r] = bi;
    }
    __syncthreads();
  }
}

// ---------------- K5: mixture: angles -> cos -> m_t (block per row) ----------------
__global__ __launch_bounds__(256) void k_mix(const float* __restrict__ h_int, const int* __restrict__ idx,
                                             const float* __restrict__ Wm_enc, const float* __restrict__ theta,
                                             const float* __restrict__ Wm_dec, const float* __restrict__ b_m,
                                             unsigned short* __restrict__ A2) {
  __shared__ float hrow[1024];
  __shared__ float partial[256];
  __shared__ float expz[16];
  const int b = blockIdx.x, t = threadIdx.x;
  const int s = idx[b];
  *reinterpret_cast<floatx4*>(&hrow[t * 4]) =
      *reinterpret_cast<const floatx4*>(&h_int[(size_t)b * 1024 + t * 4]);
  __syncthreads();
  const int q = t & 15, g = t >> 4;
  const float* We = Wm_enc + (size_t)s * 16384;
  float p = 0.f;
#pragma unroll 8
  for (int j = 0; j < 64; ++j) {
    int h = g + j * 16;
    p += hrow[h] * We[h * 16 + q];
  }
  partial[t] = p;
  __syncthreads();
  if (t < 16) {
    float a = 0.f;
#pragma unroll
    for (int g2 = 0; g2 < 16; ++g2) a += partial[g2 * 16 + t];
    a += theta[s * 16 + t];
    expz[t] = cosf(a);
  }
  __syncthreads();
  const float* Wd = Wm_dec + (size_t)s * 16384;
  float e[16];
#pragma unroll
  for (int qq = 0; qq < 16; ++qq) e[qq] = expz[qq];
#pragma unroll
  for (int r = 0; r < 4; ++r) {
    int h = r * 256 + t;
    float v = b_m[h];
#pragma unroll
    for (int qq = 0; qq < 16; ++qq) v += e[qq] * Wd[qq * 1024 + h];
    A2[(size_t)b * 2048 + 1024 + h] = f2bf(tanhf(v));
  }
}

// ---------------- K6: goh = A2 @ BT^T + b_og -> tanh/split epilogue ----------------
// 128x128 tile, BK=32, 4 waves. 3-buffer LDS, depth-2 prefetch, counted vmcnt.
__global__ __launch_bounds__(256) void k_gemm4(const unsigned short* __restrict__ A2,
                                               const unsigned short* __restrict__ BT,
                                               const float* __restrict__ b_og, float* __restrict__ out) {
  __shared__ __align__(16) unsigned short As[3 * 4096];
  __shared__ __align__(16) unsigned short Bs[3 * 4096];
  const int t = threadIdx.x;
  const int lane = t & 63, w = t >> 6;
  const int wm = w >> 1, wn = w & 1;
  const int m0 = blockIdx.x * 128, n0 = blockIdx.y * 128;
  const int lr = lane & 15, lk = lane >> 4;
  floatx4 acc[4][4];
  floatx4 zero = {0.f, 0.f, 0.f, 0.f};
#pragma unroll
  for (int mi = 0; mi < 4; ++mi)
#pragma unroll
    for (int ni = 0; ni < 4; ++ni) acc[mi][ni] = zero;

  auto stage = [&](int p, int kt) {   // 4 GLL per thread
    const int k0 = kt * 32;
#pragma unroll
    for (int j = 0; j < 2; ++j) {
      int cc = j * 256 + t;
      int row = cc >> 2, sl = cc & 3;
      int sg = sl ^ ((row >> 1) & 3);
      size_t ga = (size_t)(m0 + row) * 2048 + k0 + sg * 8;
      size_t gb = (size_t)(n0 + row) * 2048 + k0 + sg * 8;
      GLL(A2 + ga, &As[p * 4096 + cc * 8]);
      GLL(BT + gb, &Bs[p * 4096 + cc * 8]);
    }
  };
  auto compute = [&](int p) {
    short8 af[4], bf[4];
#pragma unroll
    for (int mi = 0; mi < 4; ++mi) {
      int row = wm * 64 + mi * 16 + lr;
      int sl = lk ^ ((row >> 1) & 3);
      af[mi] = *reinterpret_cast<const short8*>(&As[p * 4096 + row * 32 + sl * 8]);
    }
#pragma unroll
    for (int ni = 0; ni < 4; ++ni) {
      int row = wn * 64 + ni * 16 + lr;
      int sl = lk ^ ((row >> 1) & 3);
      bf[ni] = *reinterpret_cast<const short8*>(&Bs[p * 4096 + row * 32 + sl * 8]);
    }
#pragma unroll
    for (int mi = 0; mi < 4; ++mi)
#pragma unroll
      for (int ni = 0; ni < 4; ++ni)
        acc[mi][ni] = __builtin_amdgcn_mfma_f32_16x16x32_bf16(af[mi], bf[ni], acc[mi][ni], 0, 0, 0);
  };

  stage(0, 0);
  stage(1, 1);
  for (int kt = 0; kt < 64; ++kt) {
    __builtin_amdgcn_sched_barrier(0);
    if (kt < 63) {
      asm volatile("s_waitcnt vmcnt(4)" ::: "memory");
    } else {
      asm volatile("s_waitcnt vmcnt(0)" ::: "memory");
    }
    __builtin_amdgcn_s_barrier();
    __builtin_amdgcn_sched_barrier(0);
    if (kt + 2 < 64) stage((kt + 2) % 3, kt + 2);
    compute(kt % 3);
  }

#pragma unroll
  for (int mi = 0; mi < 4; ++mi) {
#pragma unroll
    for (int ni = 0; ni < 4; ++ni) {
      int gn = n0 + wn * 64 + ni * 16 + lr;
      float bias = b_og[gn];
      int gmb = m0 + wm * 64 + mi * 16 + lk * 4;
#pragma unroll
      for (int j = 0; j < 4; ++j) {
        int gm = gmb + j;
        float v = acc[mi][ni][j] + bias;
        if (gn < 1024) {
          out[OUT_H_OFF + (size_t)gm * 1024 + gn] = tanhf(v);  // h_next
        } else {
          out[(size_t)gm * 1024 + (gn - 1024)] = v;            // y_t
        }
      }
    }
  }
}

extern "C" void kernel_launch(void* const* d_in, const int* in_sizes, int n_in,
                              void* d_out, int out_size, void* d_ws, size_t ws_size,
                              hipStream_t stream) {
  (void)in_sizes; (void)n_in; (void)out_size;
  const float* x_t    = (const float*)d_in[0];
  const float* h_prev = (const float*)d_in[1];
  const float* W_in   = (const float*)d_in[2];
  const float* b_in   = (const float*)d_in[3];
  const float* W_q    = (const float*)d_in[4];
  const float* b_q    = (const float*)d_in[5];
  const float* W_sel  = (const float*)d_in[6];
  const float* b_sel  = (const float*)d_in[7];
  const float* Wm_enc = (const float*)d_in[8];
  const float* theta  = (const float*)d_in[9];
  const float* Wm_dec = (const float*)d_in[10];
  const float* b_m    = (const float*)d_in[11];
  const float* W_og   = (const float*)d_in[12];
  const float* b_og   = (const float*)d_in[13];
  float* out = (float*)d_out;

  char* ws = (char*)d_ws;
  float* h_int          = (float*)(ws);
  unsigned short* A2    = (unsigned short*)(ws + ((size_t)16 << 20));
  unsigned short* BT    = (unsigned short*)(ws + ((size_t)32 << 20));
  float* Wqs            = (float*)(ws + ((size_t)40 << 20));
  int* idx              = (int*)(ws + ((size_t)41 << 20));
  int* counter          = (int*)(ws + ((size_t)41 << 20) + 16384);
  int* list             = (int*)(ws + ((size_t)41 << 20) + 16384 + 64);
  unsigned short* Ahi   = (unsigned short*)(ws + ((size_t)42 << 20));
  unsigned short* Alo   = (unsigned short*)(ws + ((size_t)58 << 20));
  unsigned short* BThi  = (unsigned short*)(ws + ((size_t)74 << 20));
  unsigned short* BTlo  = (unsigned short*)(ws + ((size_t)78 << 20));
  float* fix_scratch    = (float*)(ws + ((size_t)42 << 20));   // reuses Ahi after gemm1m

  const bool use_mfma = ws_size >= ((size_t)82 << 20);

  hipLaunchKernelGGL(k_transpose, dim3(32, 32), dim3(256), 0, stream, W_og, BT);
  hipLaunchKernelGGL(k_wqs, dim3(257), dim3(256), 0, stream, W_q, b_q, W_sel, b_sel, Wqs);
  hipMemsetAsync(counter, 0, 4, stream);

  if (use_mfma) {
    hipLaunchKernelGGL(k_convA, dim3(2048), dim3(256), 0, stream, x_t, h_prev, Ahi, Alo);
    hipLaunchKernelGGL(k_convB, dim3(32, 16), dim3(256), 0, stream, W_in, BThi, BTlo);
    hipLaunchKernelGGL(k_gemm1m, dim3(32, 16), dim3(256), 0, stream,
                       Ahi, Alo, BThi, BTlo, b_in, h_int, A2);
    hipLaunchKernelGGL(k_argmax, dim3(128), dim3(256), 0, stream, h_int, Wqs, idx, counter, list, TAU);
    hipLaunchKernelGGL(k_fixA, dim3(512), dim3(256), 0, stream,
                       x_t, h_prev, W_in, counter, list, fix_scratch);
    hipLaunchKernelGGL(k_fixB, dim3(64), dim3(256), 0, stream,
                       fix_scratch, b_in, Wqs, counter, list, idx);
  } else {
    hipLaunchKernelGGL(k_gemm1, dim3(32, 16), dim3(256), 0, stream, x_t, h_prev, W_in, b_in, h_int, A2);
    hipLaunchKernelGGL(k_argmax, dim3(128), dim3(256), 0, stream, h_int, Wqs, idx, counter, list, 0.0f);
  }

  hipLaunchKernelGGL(k_mix, dim3(4096), dim3(256), 0, stream, h_int, idx, Wm_enc, theta, Wm_dec, b_m, A2);
  hipLaunchKernelGGL(k_gemm4, dim3(32, 16), dim3(256), 0, stream, A2, BT, b_og, out);
}